// Round 7
// baseline (180.030 us; speedup 1.0000x reference)
//
#include <hip/hip_runtime.h>
#include <hip/hip_bf16.h>

#define T_LEN 2048
#define BSZ 4
#define EMB 256
#define HDIM 32
#define QSCALE 0.17677669529663687f
#define LOG2E 1.4426950408889634f

using bf16x8 = __attribute__((ext_vector_type(8))) short;
using bf16x4 = __attribute__((ext_vector_type(4))) short;
using f32x4 = __attribute__((ext_vector_type(4))) float;

static __device__ __forceinline__ unsigned fasu(float f) {
  union { float f; unsigned u; } c; c.f = f; return c.u;
}
// pack two floats to packed bf16 pair (round-half-up) in ONE v_perm + 2 adds
static __device__ __forceinline__ unsigned pack2r(float lo, float hi) {
  return __builtin_amdgcn_perm(fasu(hi) + 0x8000u, fasu(lo) + 0x8000u, 0x07060302u);
}
static __device__ __forceinline__ unsigned short bfr(float x) {
  return (unsigned short)((fasu(x) + 0x8000u) >> 16);
}

// all 4 weight matrices fp32->bf16 in one launch (blockIdx.y selects)
__global__ __launch_bounds__(256) void cvt_w4(const float* __restrict__ s0, const float* __restrict__ s1,
                                              const float* __restrict__ s2, const float* __restrict__ s3,
                                              unsigned* __restrict__ d0, unsigned* __restrict__ d1,
                                              unsigned* __restrict__ d2, unsigned* __restrict__ d3) {
  const float* src = blockIdx.y == 0 ? s0 : blockIdx.y == 1 ? s1 : blockIdx.y == 2 ? s2 : s3;
  unsigned* dst = blockIdx.y == 0 ? d0 : blockIdx.y == 1 ? d1 : blockIdx.y == 2 ? d2 : d3;
  int i = blockIdx.x * 256 + threadIdx.x;
  float4 v = ((const float4*)src)[i];
  uint2 o; o.x = pack2r(v.x, v.y); o.y = pack2r(v.z, v.w);
  ((uint2*)dst)[i] = o;
}

// fused QKV projection: z=0 -> qh [bh][t][32] (scaled by QSCALE*LOG2E), z=1 -> kh, z=2 -> vt [bh][32][t]
__global__ __launch_bounds__(256) void qkv_proj(
    const float* __restrict__ Aq, const float* __restrict__ Ak, const float* __restrict__ Av,
    const unsigned short* __restrict__ Wq, const unsigned short* __restrict__ Wk, const unsigned short* __restrict__ Wv,
    const float* __restrict__ bq, const float* __restrict__ bk, const float* __restrict__ bv,
    unsigned short* __restrict__ qh, unsigned short* __restrict__ kh, unsigned short* __restrict__ vt) {
  __shared__ __align__(16) unsigned short smem[64 * 72];  // [m_local][n_local], stride 72 (16B-aligned rows)
  const int z = blockIdx.z;
  const float* A = z == 0 ? Aq : z == 1 ? Ak : Av;
  const unsigned short* W = z == 0 ? Wq : z == 1 ? Wk : Wv;
  const float* bias = z == 0 ? bq : z == 1 ? bk : bv;
  const float ascale = z == 0 ? QSCALE * LOG2E : 1.0f;
  const float bscale = z == 0 ? LOG2E : 1.0f;
  const int lane = threadIdx.x & 63;
  const int wave = threadIdx.x >> 6;
  const int quad = lane >> 4;
  const int l16 = lane & 15;
  const int m0b = blockIdx.x * 64;
  const int m0 = m0b + wave * 16;
  const int n0 = blockIdx.y * 64;
  f32x4 acc0 = {0.f, 0.f, 0.f, 0.f}, acc1 = acc0, acc2 = acc0, acc3 = acc0;
  const float* arow = A + (m0 + l16) * EMB;
#pragma unroll
  for (int k0 = 0; k0 < EMB; k0 += 32) {
    const float4* ap = (const float4*)(arow + k0 + quad * 8);
    float4 a0 = ap[0], a1 = ap[1];
    union { unsigned u[4]; bf16x8 v; } af;
    af.u[0] = pack2r(a0.x * ascale, a0.y * ascale);
    af.u[1] = pack2r(a0.z * ascale, a0.w * ascale);
    af.u[2] = pack2r(a1.x * ascale, a1.y * ascale);
    af.u[3] = pack2r(a1.z * ascale, a1.w * ascale);
    const unsigned short* wbase = W + k0 + quad * 8;
    bf16x8 b0 = *(const bf16x8*)(wbase + (n0 + 0 + l16) * EMB);
    bf16x8 b1 = *(const bf16x8*)(wbase + (n0 + 16 + l16) * EMB);
    bf16x8 b2 = *(const bf16x8*)(wbase + (n0 + 32 + l16) * EMB);
    bf16x8 b3 = *(const bf16x8*)(wbase + (n0 + 48 + l16) * EMB);
    acc0 = __builtin_amdgcn_mfma_f32_16x16x32_bf16(af.v, b0, acc0, 0, 0, 0);
    acc1 = __builtin_amdgcn_mfma_f32_16x16x32_bf16(af.v, b1, acc1, 0, 0, 0);
    acc2 = __builtin_amdgcn_mfma_f32_16x16x32_bf16(af.v, b2, acc2, 0, 0, 0);
    acc3 = __builtin_amdgcn_mfma_f32_16x16x32_bf16(af.v, b3, acc3, 0, 0, 0);
  }
  f32x4 accs[4] = {acc0, acc1, acc2, acc3};
#pragma unroll
  for (int nt = 0; nt < 4; ++nt) {
    float bn = bias[n0 + nt * 16 + l16] * bscale;
#pragma unroll
    for (int r = 0; r < 4; ++r)
      smem[(wave * 16 + quad * 4 + r) * 72 + nt * 16 + l16] = bfr(accs[nt][r] + bn);
  }
  __syncthreads();
  if (z < 2) {
    // coalesced 32B/thread stores to [bh][t][hd]; 16-col chunk stays inside one head
    int row = threadIdx.x >> 2, seg = threadIdx.x & 3;
    int m = m0b + row, t = m >> 2, b = m & 3;
    int n = n0 + seg * 16, h = n >> 5, hd = n & 31;
    unsigned short* dst = (z == 0 ? qh : kh) + (((b << 3) + h) * T_LEN + t) * HDIM + hd;
    *(bf16x8*)(dst + 0) = *(const bf16x8*)(smem + row * 72 + seg * 16 + 0);
    *(bf16x8*)(dst + 8) = *(const bf16x8*)(smem + row * 72 + seg * 16 + 8);
  } else {
    // transposed [bh][hd][t]: each thread emits one 32B t-contiguous chunk
    int n = threadIdx.x >> 2, b = threadIdx.x & 3;
    unsigned w[8];
#pragma unroll
    for (int i = 0; i < 8; ++i) {
      unsigned lo = smem[((2 * i) * 4 + b) * 72 + n];
      unsigned hi = smem[((2 * i + 1) * 4 + b) * 72 + n];
      w[i] = lo | (hi << 16);
    }
    int nf = n0 + n, h = nf >> 5, hd = nf & 31;
    int tbase = m0b >> 2;
    unsigned* base = (unsigned*)(vt + (((b << 3) + h) * HDIM + hd) * T_LEN + tbase);
    ((uint4*)base)[0] = make_uint4(w[0], w[1], w[2], w[3]);
    ((uint4*)base)[1] = make_uint4(w[4], w[5], w[6], w[7]);
  }
}

// out = A @ W^T + bias ; A bf16 [8192][256], out fp32 [8192][256], float4 stores via LDS
__global__ __launch_bounds__(256) void out_gemm(const unsigned short* __restrict__ A,
                                                const unsigned short* __restrict__ W,
                                                const float* __restrict__ bias,
                                                float* __restrict__ out) {
  __shared__ __align__(16) float smem[64 * 68];  // stride 68 floats = 272B (16B-aligned)
  const int lane = threadIdx.x & 63;
  const int wave = threadIdx.x >> 6;
  const int quad = lane >> 4;
  const int l16 = lane & 15;
  const int m0b = blockIdx.x * 64;
  const int m0 = m0b + wave * 16;
  const int n0 = blockIdx.y * 64;
  f32x4 acc0 = {0.f, 0.f, 0.f, 0.f}, acc1 = acc0, acc2 = acc0, acc3 = acc0;
  const unsigned short* arow = A + (m0 + l16) * EMB;
#pragma unroll
  for (int k0 = 0; k0 < EMB; k0 += 32) {
    bf16x8 af = *(const bf16x8*)(arow + k0 + quad * 8);
    const unsigned short* wbase = W + k0 + quad * 8;
    bf16x8 b0 = *(const bf16x8*)(wbase + (n0 + 0 + l16) * EMB);
    bf16x8 b1 = *(const bf16x8*)(wbase + (n0 + 16 + l16) * EMB);
    bf16x8 b2 = *(const bf16x8*)(wbase + (n0 + 32 + l16) * EMB);
    bf16x8 b3 = *(const bf16x8*)(wbase + (n0 + 48 + l16) * EMB);
    acc0 = __builtin_amdgcn_mfma_f32_16x16x32_bf16(af, b0, acc0, 0, 0, 0);
    acc1 = __builtin_amdgcn_mfma_f32_16x16x32_bf16(af, b1, acc1, 0, 0, 0);
    acc2 = __builtin_amdgcn_mfma_f32_16x16x32_bf16(af, b2, acc2, 0, 0, 0);
    acc3 = __builtin_amdgcn_mfma_f32_16x16x32_bf16(af, b3, acc3, 0, 0, 0);
  }
  f32x4 accs[4] = {acc0, acc1, acc2, acc3};
#pragma unroll
  for (int nt = 0; nt < 4; ++nt) {
    float bn = bias[n0 + nt * 16 + l16];
#pragma unroll
    for (int r = 0; r < 4; ++r)
      smem[(wave * 16 + quad * 4 + r) * 68 + nt * 16 + l16] = accs[nt][r] + bn;
  }
  __syncthreads();
  int row = threadIdx.x >> 2, seg = threadIdx.x & 3;
  const float4* srcp = (const float4*)(smem + row * 68 + seg * 16);
  float4* dstp = (float4*)(out + (m0b + row) * EMB + n0 + seg * 16);
#pragma unroll
  for (int i = 0; i < 4; ++i) dstp[i] = srcp[i];
}

// Flash attention: V LDS-staged (double-buffered 128-key chunks), K DIRECT from
// global — K rows [bh][t][32] are fully coalesced (16 rows x 64B = 1KB/wave-load)
// and identical across the block's 4 waves -> L1 broadcast; only V's 4KB-strided
// rows need the LDS transpose-staging. Hot loop: global K b128 (hoisted by unroll)
// + 2 ds_read b64 (V) -> S^T=K.Q^T (16x16x32) -> exp2 (log2-domain, no max) ->
// pack -> PV + denominator via 16x16x16 MFMA whose B-operand layout equals the
// S^T C-layout (zero cross-lane ops). 1 barrier per 128-key chunk.
__global__ __launch_bounds__(256) void flash_attn(const unsigned short* __restrict__ qh,
                                                  const unsigned short* __restrict__ kh,
                                                  const unsigned short* __restrict__ vt,
                                                  unsigned short* __restrict__ aout) {
  __shared__ __align__(16) unsigned short vbuf[2][32 * 136];      // 2 x 8.5 KB, V [d][key], stride 136
  const int tid = threadIdx.x;
  const int lane = tid & 63;
  const int wave = tid >> 6;
  const int quad = lane >> 4;
  const int l16 = lane & 15;
  const int bh = blockIdx.x;
  const int q0 = blockIdx.y * 64 + wave * 16;
  const unsigned short* qs = qh + bh * (T_LEN * HDIM);
  const unsigned short* ks = kh + bh * (T_LEN * HDIM);
  const unsigned short* vs = vt + bh * (T_LEN * HDIM);
  const bf16x8 qf = *(const bf16x8*)(qs + (q0 + l16) * HDIM + quad * 8);
  f32x4 o0 = {0.f, 0.f, 0.f, 0.f}, o1 = o0, la = o0;
  const f32x4 zero = o0;
  bf16x4 ones;
  ones[0] = ones[1] = ones[2] = ones[3] = (short)0x3F80;  // bf16 1.0

  const int vrow = tid >> 4;          // 0..15 (and +16 in second shot)
  const int vcol = (tid & 15) * 8;    // 16B units along keys

  // stage V chunk 0
  {
    uint4 va = *(const uint4*)(vs + vrow * T_LEN + vcol);
    uint4 vb = *(const uint4*)(vs + (vrow + 16) * T_LEN + vcol);
    *(uint4*)(&vbuf[0][vrow * 136 + vcol]) = va;
    *(uint4*)(&vbuf[0][(vrow + 16) * 136 + vcol]) = vb;
  }
  __syncthreads();

  for (int chunk = 0; chunk < 16; ++chunk) {
    const int buf = chunk & 1;
    uint4 va, vb;
    const bool pf = (chunk + 1) < 16;
    if (pf) {
      const int kk0 = (chunk + 1) * 128;
      va = *(const uint4*)(vs + vrow * T_LEN + kk0 + vcol);
      vb = *(const uint4*)(vs + (vrow + 16) * T_LEN + kk0 + vcol);
    }
    const unsigned short* kc = ks + chunk * 128 * HDIM;
#pragma unroll
    for (int it = 0; it < 8; ++it) {
      const int kkl = it * 16;
      bf16x8 kf = *(const bf16x8*)(kc + (kkl + l16) * HDIM + quad * 8);
      bf16x4 vfa = *(const bf16x4*)(&vbuf[buf][l16 * 136 + kkl + quad * 4]);
      bf16x4 vfb = *(const bf16x4*)(&vbuf[buf][(l16 + 16) * 136 + kkl + quad * 4]);
      f32x4 s = __builtin_amdgcn_mfma_f32_16x16x32_bf16(kf, qf, zero, 0, 0, 0);
      union { unsigned u[2]; bf16x4 v; } pp;
      float a = __builtin_amdgcn_exp2f(s[0]), b = __builtin_amdgcn_exp2f(s[1]);
      float c = __builtin_amdgcn_exp2f(s[2]), d = __builtin_amdgcn_exp2f(s[3]);
      pp.u[0] = pack2r(a, b); pp.u[1] = pack2r(c, d);
      o0 = __builtin_amdgcn_mfma_f32_16x16x16bf16_1k(vfa, pp.v, o0, 0, 0, 0);
      o1 = __builtin_amdgcn_mfma_f32_16x16x16bf16_1k(vfb, pp.v, o1, 0, 0, 0);
      la = __builtin_amdgcn_mfma_f32_16x16x16bf16_1k(ones, pp.v, la, 0, 0, 0);
    }
    if (pf) {
      const int nb = buf ^ 1;
      *(uint4*)(&vbuf[nb][vrow * 136 + vcol]) = va;
      *(uint4*)(&vbuf[nb][(vrow + 16) * 136 + vcol]) = vb;
    }
    __syncthreads();
  }

  // epilogue: normalize + O^T (C-layout: d=quad*4+r, q=l16) -> row-major [q][d]
  const float inv = 1.f / la[0];
  const int srcA = l16 + ((quad & 1) << 5);
  const int srcB = srcA + 16;
  const bool lowq = quad < 2;
  unsigned oa = pack2r(o0[0] * inv, o0[1] * inv), ob = pack2r(o0[2] * inv, o0[3] * inv);
  unsigned oc = pack2r(o1[0] * inv, o1[1] * inv), od = pack2r(o1[2] * inv, o1[3] * inv);
  union { unsigned u[4]; bf16x8 v; } of;
  unsigned ta, tc;
  ta = __shfl(oa, srcA); tc = __shfl(oc, srcA); of.u[0] = lowq ? ta : tc;
  ta = __shfl(ob, srcA); tc = __shfl(od, srcA); of.u[1] = lowq ? ta : tc;
  ta = __shfl(oa, srcB); tc = __shfl(oc, srcB); of.u[2] = lowq ? ta : tc;
  ta = __shfl(ob, srcB); tc = __shfl(od, srcB); of.u[3] = lowq ? ta : tc;
  const int t = q0 + l16;
  const int b = bh >> 3, h = bh & 7;
  *(bf16x8*)(aout + (t * BSZ + b) * EMB + h * HDIM + quad * 8) = of.v;
}

extern "C" void kernel_launch(void* const* d_in, const int* in_sizes, int n_in,
                              void* d_out, int out_size, void* d_ws, size_t ws_size,
                              hipStream_t stream) {
  const float* q  = (const float*)d_in[0];
  const float* k  = (const float*)d_in[1];
  const float* v  = (const float*)d_in[2];
  const float* Wq = (const float*)d_in[3];
  const float* bq = (const float*)d_in[4];
  const float* Wk = (const float*)d_in[5];
  const float* bk = (const float*)d_in[6];
  const float* Wv = (const float*)d_in[7];
  const float* bv = (const float*)d_in[8];
  const float* Wp = (const float*)d_in[9];
  const float* bp = (const float*)d_in[10];
  float* out = (float*)d_out;

  char* ws = (char*)d_ws;
  unsigned short* qh   = (unsigned short*)(ws);                    // 4 MiB
  unsigned short* kh   = (unsigned short*)(ws + (4u << 20));       // 4 MiB
  unsigned short* vt   = (unsigned short*)(ws + (8u << 20));       // 4 MiB
  unsigned short* aout = (unsigned short*)(ws + (12u << 20));      // 4 MiB
  unsigned short* wqb  = (unsigned short*)(ws + (16u << 20));      // 4 x 128 KiB
  unsigned short* wkb  = wqb + 65536;
  unsigned short* wvb  = wqb + 2 * 65536;
  unsigned short* wpb  = wqb + 3 * 65536;

  cvt_w4<<<dim3(64, 4), 256, 0, stream>>>(Wq, Wk, Wv, Wp,
                                          (unsigned*)wqb, (unsigned*)wkb,
                                          (unsigned*)wvb, (unsigned*)wpb);
  qkv_proj<<<dim3(128, 4, 3), 256, 0, stream>>>(q, k, v, wqb, wkb, wvb, bq, bk, bv, qh, kh, vt);
  flash_attn<<<dim3(32, 32), 256, 0, stream>>>(qh, kh, vt, aout);
  out_gemm<<<dim3(128, 4), 256, 0, stream>>>(aout, wpb, bp, out);
}

// Round 8
// 166.795 us; speedup vs baseline: 1.0794x; 1.0794x over previous
//
#include <hip/hip_runtime.h>
#include <hip/hip_bf16.h>

#define T_LEN 2048
#define BSZ 4
#define EMB 256
#define HDIM 32
#define QSCALE 0.17677669529663687f
#define LOG2E 1.4426950408889634f

using bf16x8 = __attribute__((ext_vector_type(8))) short;
using bf16x4 = __attribute__((ext_vector_type(4))) short;
using f32x4 = __attribute__((ext_vector_type(4))) float;

static __device__ __forceinline__ unsigned fasu(float f) {
  union { float f; unsigned u; } c; c.f = f; return c.u;
}
// pack two floats to packed bf16 pair (round-half-up) in ONE v_perm + 2 adds
static __device__ __forceinline__ unsigned pack2r(float lo, float hi) {
  return __builtin_amdgcn_perm(fasu(hi) + 0x8000u, fasu(lo) + 0x8000u, 0x07060302u);
}
static __device__ __forceinline__ unsigned short bfr(float x) {
  return (unsigned short)((fasu(x) + 0x8000u) >> 16);
}

// all 4 weight matrices fp32->bf16 in one launch (blockIdx.y selects)
__global__ __launch_bounds__(256) void cvt_w4(const float* __restrict__ s0, const float* __restrict__ s1,
                                              const float* __restrict__ s2, const float* __restrict__ s3,
                                              unsigned* __restrict__ d0, unsigned* __restrict__ d1,
                                              unsigned* __restrict__ d2, unsigned* __restrict__ d3) {
  const float* src = blockIdx.y == 0 ? s0 : blockIdx.y == 1 ? s1 : blockIdx.y == 2 ? s2 : s3;
  unsigned* dst = blockIdx.y == 0 ? d0 : blockIdx.y == 1 ? d1 : blockIdx.y == 2 ? d2 : d3;
  int i = blockIdx.x * 256 + threadIdx.x;
  float4 v = ((const float4*)src)[i];
  uint2 o; o.x = pack2r(v.x, v.y); o.y = pack2r(v.z, v.w);
  ((uint2*)dst)[i] = o;
}

// fused QKV projection: z=0 -> qh [bh][t][32] (scaled by QSCALE*LOG2E), z=1 -> kh, z=2 -> vt [bh][32][t]
__global__ __launch_bounds__(256) void qkv_proj(
    const float* __restrict__ Aq, const float* __restrict__ Ak, const float* __restrict__ Av,
    const unsigned short* __restrict__ Wq, const unsigned short* __restrict__ Wk, const unsigned short* __restrict__ Wv,
    const float* __restrict__ bq, const float* __restrict__ bk, const float* __restrict__ bv,
    unsigned short* __restrict__ qh, unsigned short* __restrict__ kh, unsigned short* __restrict__ vt) {
  __shared__ __align__(16) unsigned short smem[64 * 72];  // [m_local][n_local], stride 72 (16B-aligned rows)
  const int z = blockIdx.z;
  const float* A = z == 0 ? Aq : z == 1 ? Ak : Av;
  const unsigned short* W = z == 0 ? Wq : z == 1 ? Wk : Wv;
  const float* bias = z == 0 ? bq : z == 1 ? bk : bv;
  const float ascale = z == 0 ? QSCALE * LOG2E : 1.0f;
  const float bscale = z == 0 ? LOG2E : 1.0f;
  const int lane = threadIdx.x & 63;
  const int wave = threadIdx.x >> 6;
  const int quad = lane >> 4;
  const int l16 = lane & 15;
  const int m0b = blockIdx.x * 64;
  const int m0 = m0b + wave * 16;
  const int n0 = blockIdx.y * 64;
  f32x4 acc0 = {0.f, 0.f, 0.f, 0.f}, acc1 = acc0, acc2 = acc0, acc3 = acc0;
  const float* arow = A + (m0 + l16) * EMB;
#pragma unroll
  for (int k0 = 0; k0 < EMB; k0 += 32) {
    const float4* ap = (const float4*)(arow + k0 + quad * 8);
    float4 a0 = ap[0], a1 = ap[1];
    union { unsigned u[4]; bf16x8 v; } af;
    af.u[0] = pack2r(a0.x * ascale, a0.y * ascale);
    af.u[1] = pack2r(a0.z * ascale, a0.w * ascale);
    af.u[2] = pack2r(a1.x * ascale, a1.y * ascale);
    af.u[3] = pack2r(a1.z * ascale, a1.w * ascale);
    const unsigned short* wbase = W + k0 + quad * 8;
    bf16x8 b0 = *(const bf16x8*)(wbase + (n0 + 0 + l16) * EMB);
    bf16x8 b1 = *(const bf16x8*)(wbase + (n0 + 16 + l16) * EMB);
    bf16x8 b2 = *(const bf16x8*)(wbase + (n0 + 32 + l16) * EMB);
    bf16x8 b3 = *(const bf16x8*)(wbase + (n0 + 48 + l16) * EMB);
    acc0 = __builtin_amdgcn_mfma_f32_16x16x32_bf16(af.v, b0, acc0, 0, 0, 0);
    acc1 = __builtin_amdgcn_mfma_f32_16x16x32_bf16(af.v, b1, acc1, 0, 0, 0);
    acc2 = __builtin_amdgcn_mfma_f32_16x16x32_bf16(af.v, b2, acc2, 0, 0, 0);
    acc3 = __builtin_amdgcn_mfma_f32_16x16x32_bf16(af.v, b3, acc3, 0, 0, 0);
  }
  f32x4 accs[4] = {acc0, acc1, acc2, acc3};
#pragma unroll
  for (int nt = 0; nt < 4; ++nt) {
    float bn = bias[n0 + nt * 16 + l16] * bscale;
#pragma unroll
    for (int r = 0; r < 4; ++r)
      smem[(wave * 16 + quad * 4 + r) * 72 + nt * 16 + l16] = bfr(accs[nt][r] + bn);
  }
  __syncthreads();
  if (z < 2) {
    // coalesced 32B/thread stores to [bh][t][hd]; 16-col chunk stays inside one head
    int row = threadIdx.x >> 2, seg = threadIdx.x & 3;
    int m = m0b + row, t = m >> 2, b = m & 3;
    int n = n0 + seg * 16, h = n >> 5, hd = n & 31;
    unsigned short* dst = (z == 0 ? qh : kh) + (((b << 3) + h) * T_LEN + t) * HDIM + hd;
    *(bf16x8*)(dst + 0) = *(const bf16x8*)(smem + row * 72 + seg * 16 + 0);
    *(bf16x8*)(dst + 8) = *(const bf16x8*)(smem + row * 72 + seg * 16 + 8);
  } else {
    // transposed [bh][hd][t]: each thread emits one 32B t-contiguous chunk
    int n = threadIdx.x >> 2, b = threadIdx.x & 3;
    unsigned w[8];
#pragma unroll
    for (int i = 0; i < 8; ++i) {
      unsigned lo = smem[((2 * i) * 4 + b) * 72 + n];
      unsigned hi = smem[((2 * i + 1) * 4 + b) * 72 + n];
      w[i] = lo | (hi << 16);
    }
    int nf = n0 + n, h = nf >> 5, hd = nf & 31;
    int tbase = m0b >> 2;
    unsigned* base = (unsigned*)(vt + (((b << 3) + h) * HDIM + hd) * T_LEN + tbase);
    ((uint4*)base)[0] = make_uint4(w[0], w[1], w[2], w[3]);
    ((uint4*)base)[1] = make_uint4(w[4], w[5], w[6], w[7]);
  }
}

// out = A @ W^T + bias ; A bf16 [8192][256], out fp32 [8192][256], float4 stores via LDS
__global__ __launch_bounds__(256) void out_gemm(const unsigned short* __restrict__ A,
                                                const unsigned short* __restrict__ W,
                                                const float* __restrict__ bias,
                                                float* __restrict__ out) {
  __shared__ __align__(16) float smem[64 * 68];  // stride 68 floats = 272B (16B-aligned)
  const int lane = threadIdx.x & 63;
  const int wave = threadIdx.x >> 6;
  const int quad = lane >> 4;
  const int l16 = lane & 15;
  const int m0b = blockIdx.x * 64;
  const int m0 = m0b + wave * 16;
  const int n0 = blockIdx.y * 64;
  f32x4 acc0 = {0.f, 0.f, 0.f, 0.f}, acc1 = acc0, acc2 = acc0, acc3 = acc0;
  const unsigned short* arow = A + (m0 + l16) * EMB;
#pragma unroll
  for (int k0 = 0; k0 < EMB; k0 += 32) {
    bf16x8 af = *(const bf16x8*)(arow + k0 + quad * 8);
    const unsigned short* wbase = W + k0 + quad * 8;
    bf16x8 b0 = *(const bf16x8*)(wbase + (n0 + 0 + l16) * EMB);
    bf16x8 b1 = *(const bf16x8*)(wbase + (n0 + 16 + l16) * EMB);
    bf16x8 b2 = *(const bf16x8*)(wbase + (n0 + 32 + l16) * EMB);
    bf16x8 b3 = *(const bf16x8*)(wbase + (n0 + 48 + l16) * EMB);
    acc0 = __builtin_amdgcn_mfma_f32_16x16x32_bf16(af, b0, acc0, 0, 0, 0);
    acc1 = __builtin_amdgcn_mfma_f32_16x16x32_bf16(af, b1, acc1, 0, 0, 0);
    acc2 = __builtin_amdgcn_mfma_f32_16x16x32_bf16(af, b2, acc2, 0, 0, 0);
    acc3 = __builtin_amdgcn_mfma_f32_16x16x32_bf16(af, b3, acc3, 0, 0, 0);
  }
  f32x4 accs[4] = {acc0, acc1, acc2, acc3};
#pragma unroll
  for (int nt = 0; nt < 4; ++nt) {
    float bn = bias[n0 + nt * 16 + l16];
#pragma unroll
    for (int r = 0; r < 4; ++r)
      smem[(wave * 16 + quad * 4 + r) * 68 + nt * 16 + l16] = accs[nt][r] + bn;
  }
  __syncthreads();
  int row = threadIdx.x >> 2, seg = threadIdx.x & 3;
  const float4* srcp = (const float4*)(smem + row * 68 + seg * 16);
  float4* dstp = (float4*)(out + (m0b + row) * EMB + n0 + seg * 16);
#pragma unroll
  for (int i = 0; i < 4; ++i) dstp[i] = srcp[i];
}

// Flash attention: K+V LDS-staged (double-buffered 128-key chunks), 2 Q-frags
// per wave (32 q-rows) so every staged K/V byte and every LDS read feeds 2x the
// MFMA work (LDS pipe was the R6 co-bottleneck at ~13.6us chip time).
// Hot loop per 16 keys: 1 ds_read_b128 (K) + 2 ds_read_b64 (V) -> 2x S^T=K.Q^T
// (16x16x32) -> 8 exp2 (log2-domain, no max) -> 4 packs -> 6x 16x16x16 MFMA
// (PV + denominator via all-ones A; B-operand layout == S^T C-layout, zero
// cross-lane ops). Register prefetch of next chunk, 1 barrier/chunk.
__global__ __launch_bounds__(256) void flash_attn(const unsigned short* __restrict__ qh,
                                                  const unsigned short* __restrict__ kh,
                                                  const unsigned short* __restrict__ vt,
                                                  unsigned short* __restrict__ aout) {
  __shared__ __align__(16) unsigned short kbuf[2][128 * 32];      // 2 x 8 KB, flat copy of K rows
  __shared__ __align__(16) unsigned short vbuf[2][32 * 136];      // 2 x 8.5 KB, V [d][key], stride 136
  const int tid = threadIdx.x;
  const int lane = tid & 63;
  const int wave = tid >> 6;
  const int quad = lane >> 4;
  const int l16 = lane & 15;
  const int bh = blockIdx.x;
  const int q0 = blockIdx.y * 128 + wave * 32;
  const unsigned short* qs = qh + bh * (T_LEN * HDIM);
  const unsigned short* ks = kh + bh * (T_LEN * HDIM);
  const unsigned short* vs = vt + bh * (T_LEN * HDIM);
  const bf16x8 qf0 = *(const bf16x8*)(qs + (q0 + l16) * HDIM + quad * 8);
  const bf16x8 qf1 = *(const bf16x8*)(qs + (q0 + 16 + l16) * HDIM + quad * 8);
  f32x4 o00 = {0.f, 0.f, 0.f, 0.f};
  f32x4 o01 = o00, o10 = o00, o11 = o00, la0 = o00, la1 = o00;
  const f32x4 zero = o00;
  bf16x4 ones;
  ones[0] = ones[1] = ones[2] = ones[3] = (short)0x3F80;  // bf16 1.0

  const int vrow = tid >> 4;          // 0..15 (and +16 in second shot)
  const int vcol = (tid & 15) * 8;    // 16B units along keys

  // stage chunk 0
  {
    uint4 ka = *(const uint4*)(ks + tid * 8);
    uint4 kb = *(const uint4*)(ks + (tid + 256) * 8);
    uint4 va = *(const uint4*)(vs + vrow * T_LEN + vcol);
    uint4 vb = *(const uint4*)(vs + (vrow + 16) * T_LEN + vcol);
    *(uint4*)(&kbuf[0][tid * 8]) = ka;
    *(uint4*)(&kbuf[0][(tid + 256) * 8]) = kb;
    *(uint4*)(&vbuf[0][vrow * 136 + vcol]) = va;
    *(uint4*)(&vbuf[0][(vrow + 16) * 136 + vcol]) = vb;
  }
  __syncthreads();

  for (int chunk = 0; chunk < 16; ++chunk) {
    const int buf = chunk & 1;
    uint4 ka, kb, va, vb;
    const bool pf = (chunk + 1) < 16;
    if (pf) {
      const int kk0 = (chunk + 1) * 128;
      const unsigned short* kg = ks + kk0 * HDIM;
      ka = *(const uint4*)(kg + tid * 8);
      kb = *(const uint4*)(kg + (tid + 256) * 8);
      va = *(const uint4*)(vs + vrow * T_LEN + kk0 + vcol);
      vb = *(const uint4*)(vs + (vrow + 16) * T_LEN + kk0 + vcol);
    }
#pragma unroll
    for (int it = 0; it < 8; ++it) {
      const int kkl = it * 16;
      bf16x8 kf = *(const bf16x8*)(&kbuf[buf][(kkl + l16) * 32 + quad * 8]);
      bf16x4 vfa = *(const bf16x4*)(&vbuf[buf][l16 * 136 + kkl + quad * 4]);
      bf16x4 vfb = *(const bf16x4*)(&vbuf[buf][(l16 + 16) * 136 + kkl + quad * 4]);
      f32x4 s0 = __builtin_amdgcn_mfma_f32_16x16x32_bf16(kf, qf0, zero, 0, 0, 0);
      f32x4 s1 = __builtin_amdgcn_mfma_f32_16x16x32_bf16(kf, qf1, zero, 0, 0, 0);
      union { unsigned u[2]; bf16x4 v; } pp0, pp1;
      {
        float a = __builtin_amdgcn_exp2f(s0[0]), b = __builtin_amdgcn_exp2f(s0[1]);
        float c = __builtin_amdgcn_exp2f(s0[2]), d = __builtin_amdgcn_exp2f(s0[3]);
        pp0.u[0] = pack2r(a, b); pp0.u[1] = pack2r(c, d);
        a = __builtin_amdgcn_exp2f(s1[0]); b = __builtin_amdgcn_exp2f(s1[1]);
        c = __builtin_amdgcn_exp2f(s1[2]); d = __builtin_amdgcn_exp2f(s1[3]);
        pp1.u[0] = pack2r(a, b); pp1.u[1] = pack2r(c, d);
      }
      o00 = __builtin_amdgcn_mfma_f32_16x16x16bf16_1k(vfa, pp0.v, o00, 0, 0, 0);
      o01 = __builtin_amdgcn_mfma_f32_16x16x16bf16_1k(vfb, pp0.v, o01, 0, 0, 0);
      la0 = __builtin_amdgcn_mfma_f32_16x16x16bf16_1k(ones, pp0.v, la0, 0, 0, 0);
      o10 = __builtin_amdgcn_mfma_f32_16x16x16bf16_1k(vfa, pp1.v, o10, 0, 0, 0);
      o11 = __builtin_amdgcn_mfma_f32_16x16x16bf16_1k(vfb, pp1.v, o11, 0, 0, 0);
      la1 = __builtin_amdgcn_mfma_f32_16x16x16bf16_1k(ones, pp1.v, la1, 0, 0, 0);
    }
    if (pf) {
      const int nb = buf ^ 1;
      *(uint4*)(&kbuf[nb][tid * 8]) = ka;
      *(uint4*)(&kbuf[nb][(tid + 256) * 8]) = kb;
      *(uint4*)(&vbuf[nb][vrow * 136 + vcol]) = va;
      *(uint4*)(&vbuf[nb][(vrow + 16) * 136 + vcol]) = vb;
    }
    __syncthreads();
  }

  // epilogue: normalize + O^T (C-layout: d=quad*4+r, q=l16) -> row-major [q][d]
  const int srcA = l16 + ((quad & 1) << 5);
  const int srcB = srcA + 16;
  const bool lowq = quad < 2;
  const int b = bh >> 3, h = bh & 7;
#pragma unroll
  for (int f = 0; f < 2; ++f) {
    f32x4 oh0 = f == 0 ? o00 : o10;
    f32x4 oh1 = f == 0 ? o01 : o11;
    const float inv = 1.f / (f == 0 ? la0[0] : la1[0]);
    unsigned oa = pack2r(oh0[0] * inv, oh0[1] * inv), ob = pack2r(oh0[2] * inv, oh0[3] * inv);
    unsigned oc = pack2r(oh1[0] * inv, oh1[1] * inv), od = pack2r(oh1[2] * inv, oh1[3] * inv);
    union { unsigned u[4]; bf16x8 v; } of;
    unsigned ta, tc;
    ta = __shfl(oa, srcA); tc = __shfl(oc, srcA); of.u[0] = lowq ? ta : tc;
    ta = __shfl(ob, srcA); tc = __shfl(od, srcA); of.u[1] = lowq ? ta : tc;
    ta = __shfl(oa, srcB); tc = __shfl(oc, srcB); of.u[2] = lowq ? ta : tc;
    ta = __shfl(ob, srcB); tc = __shfl(od, srcB); of.u[3] = lowq ? ta : tc;
    const int t = q0 + f * 16 + l16;
    *(bf16x8*)(aout + (t * BSZ + b) * EMB + h * HDIM + quad * 8) = of.v;
  }
}

extern "C" void kernel_launch(void* const* d_in, const int* in_sizes, int n_in,
                              void* d_out, int out_size, void* d_ws, size_t ws_size,
                              hipStream_t stream) {
  const float* q  = (const float*)d_in[0];
  const float* k  = (const float*)d_in[1];
  const float* v  = (const float*)d_in[2];
  const float* Wq = (const float*)d_in[3];
  const float* bq = (const float*)d_in[4];
  const float* Wk = (const float*)d_in[5];
  const float* bk = (const float*)d_in[6];
  const float* Wv = (const float*)d_in[7];
  const float* bv = (const float*)d_in[8];
  const float* Wp = (const float*)d_in[9];
  const float* bp = (const float*)d_in[10];
  float* out = (float*)d_out;

  char* ws = (char*)d_ws;
  unsigned short* qh   = (unsigned short*)(ws);                    // 4 MiB
  unsigned short* kh   = (unsigned short*)(ws + (4u << 20));       // 4 MiB
  unsigned short* vt   = (unsigned short*)(ws + (8u << 20));       // 4 MiB
  unsigned short* aout = (unsigned short*)(ws + (12u << 20));      // 4 MiB
  unsigned short* wqb  = (unsigned short*)(ws + (16u << 20));      // 4 x 128 KiB
  unsigned short* wkb  = wqb + 65536;
  unsigned short* wvb  = wqb + 2 * 65536;
  unsigned short* wpb  = wqb + 3 * 65536;

  cvt_w4<<<dim3(64, 4), 256, 0, stream>>>(Wq, Wk, Wv, Wp,
                                          (unsigned*)wqb, (unsigned*)wkb,
                                          (unsigned*)wvb, (unsigned*)wpb);
  qkv_proj<<<dim3(128, 4, 3), 256, 0, stream>>>(q, k, v, wqb, wkb, wvb, bq, bk, bv, qh, kh, vt);
  flash_attn<<<dim3(32, 16), 256, 0, stream>>>(qh, kh, vt, aout);
  out_gemm<<<dim3(128, 4), 256, 0, stream>>>(aout, wpb, bp, out);
}